// Round 2
// baseline (824.622 us; speedup 1.0000x reference)
//
#include <hip/hip_runtime.h>
#include <stdint.h>

#define B_ 8
#define S_ 2048
#define D_ 128
#define H_ 4
#define DK_ 32

constexpr float SCALE = 0.17677669529663687f; // 1/sqrt(32)

using short8  = __attribute__((ext_vector_type(8))) short;
using ushort8 = __attribute__((ext_vector_type(8))) unsigned short;
using f32x4   = __attribute__((ext_vector_type(4))) float;

__device__ __forceinline__ uint32_t bf16b(float x) {
    uint32_t u = __builtin_bit_cast(uint32_t, x);
    return (u + 0x7fffu + ((u >> 16) & 1u)) >> 16;
}
__device__ __forceinline__ uint32_t pack2(float a, float b) {
    return bf16b(a) | (bf16b(b) << 16);
}
__device__ __forceinline__ float bf2f(unsigned short h) {
    uint32_t u = ((uint32_t)h) << 16;
    return __builtin_bit_cast(float, u);
}

// ---------------------------------------------------------------------------
// Kernel 0a: pack 5 weight matrices [128][128] f32 into bf16 MFMA-B fragment
// order: Wp[m][((nt*4+kf)*64+lane)*8+j] = bf16(W[kf*32+(lane>>4)*8+j][nt*16+(lane&15)])
// ---------------------------------------------------------------------------
__global__ __launch_bounds__(256) void pack_w_kernel(
    const float* __restrict__ W0, const float* __restrict__ W1,
    const float* __restrict__ W2, const float* __restrict__ W3,
    const float* __restrict__ W4, unsigned short* __restrict__ Wp)
{
    const float* Ws[5] = {W0, W1, W2, W3, W4};
    const float* W = Ws[blockIdx.x];
    unsigned short* dst = Wp + blockIdx.x * 16384;
    for (int flat = threadIdx.x; flat < 16384; flat += 256) {
        const int j    = flat & 7;
        const int lane = (flat >> 3) & 63;
        const int kf   = (flat >> 9) & 3;
        const int nt   = flat >> 11;
        const int k = kf * 32 + ((lane >> 4) * 8) + j;
        const int n = nt * 16 + (lane & 15);
        dst[flat] = (unsigned short)bf16b(W[k * 128 + n]);
    }
}

// ---------------------------------------------------------------------------
// Kernel 0b: bit-pack int32 bool mask -> 1 bit per position (ballot).
// mbits64[i>>6] bit l = (mask[(i&~63)+l] != 0)
// ---------------------------------------------------------------------------
__global__ __launch_bounds__(256) void pack_mask_kernel(
    const int* __restrict__ mask, unsigned long long* __restrict__ mbits64)
{
    const int tot = B_ * S_ * S_;
    const int stride = gridDim.x * 256;
    for (int i = blockIdx.x * 256 + threadIdx.x; i < tot; i += stride) {
        unsigned long long bal = __ballot(mask[i] != 0);
        if ((threadIdx.x & 63) == 0) mbits64[i >> 6] = bal;
    }
}

// ---------------------------------------------------------------------------
// Kernel 1: projections via MFMA. Block = 16 s-rows of one batch, 4 waves.
// wave0: resid = Xq@Wfc0 (fp32 out); wave1: Qb = bf16(Xq@Wq);
// wave2: Kb = bf16(Xk@Wk); wave3: Vt = bf16(Xv@Wv)^T per head.
// ---------------------------------------------------------------------------
__global__ __launch_bounds__(256) void proj_kernel(
    const float* __restrict__ Xq, const float* __restrict__ Xk,
    const float* __restrict__ Xv, const unsigned short* __restrict__ Wp,
    float* __restrict__ resid, unsigned short* __restrict__ Qb,
    unsigned short* __restrict__ Kb, unsigned short* __restrict__ Vt)
{
    const int b    = blockIdx.x >> 7;
    const int s0   = (blockIdx.x & 127) << 4;
    const int w    = threadIdx.x >> 6;
    const int lane = threadIdx.x & 63;
    const int lq   = lane & 15;
    const int g    = lane >> 4;

    const float* X = (w == 2) ? Xk : (w == 3) ? Xv : Xq;
    const float* xrow = X + ((size_t)b * S_ + s0 + lq) * D_;

    // A-fragments: A[m=s-row][k], lane m=lq, k = kf*32 + g*8 + j
    short8 afr[4];
    #pragma unroll
    for (int kf = 0; kf < 4; ++kf) {
        const float4 x0 = *(const float4*)(xrow + kf * 32 + g * 8);
        const float4 x1 = *(const float4*)(xrow + kf * 32 + g * 8 + 4);
        short8 a;
        a[0] = (short)bf16b(x0.x); a[1] = (short)bf16b(x0.y);
        a[2] = (short)bf16b(x0.z); a[3] = (short)bf16b(x0.w);
        a[4] = (short)bf16b(x1.x); a[5] = (short)bf16b(x1.y);
        a[6] = (short)bf16b(x1.z); a[7] = (short)bf16b(x1.w);
        afr[kf] = a;
    }

    const unsigned short* wp = Wp + w * 16384;

    #pragma unroll
    for (int nt = 0; nt < 8; ++nt) {
        f32x4 acc = {0.f, 0.f, 0.f, 0.f};
        #pragma unroll
        for (int kf = 0; kf < 4; ++kf) {
            const short8 bfrag = *(const short8*)(wp + ((nt * 4 + kf) * 64 + lane) * 8);
            acc = __builtin_amdgcn_mfma_f32_16x16x32_bf16(afr[kf], bfrag, acc, 0, 0, 0);
        }
        const int n = nt * 16 + lq;          // output col
        if (w == 0) {
            #pragma unroll
            for (int r = 0; r < 4; ++r)
                resid[((size_t)b * S_ + s0 + g * 4 + r) * D_ + n] = acc[r];
        } else if (w == 1) {
            const int h = n >> 5, dd = n & 31;
            #pragma unroll
            for (int r = 0; r < 4; ++r)
                Qb[((size_t)(b * H_ + h) * S_ + s0 + g * 4 + r) * DK_ + dd] =
                    (unsigned short)bf16b(acc[r]);
        } else if (w == 2) {
            const int h = n >> 5, dd = n & 31;
            #pragma unroll
            for (int r = 0; r < 4; ++r)
                Kb[((size_t)(b * H_ + h) * S_ + s0 + g * 4 + r) * DK_ + dd] =
                    (unsigned short)bf16b(acc[r]);
        } else {
            const int h = n >> 5, dd = n & 31;
            #pragma unroll
            for (int r = 0; r < 4; ++r)
                Vt[((size_t)(b * H_ + h) * DK_ + dd) * S_ + s0 + g * 4 + r] =
                    (unsigned short)bf16b(acc[r]);
        }
    }
}

// ---------------------------------------------------------------------------
// Kernel 2: attention. One block per (b,h, 16-row q-tile). 256 thr = 4 waves.
// Wave w covers kv in [w*512, w*512+512).
// ---------------------------------------------------------------------------
__global__ __launch_bounds__(256) void attn_kernel(
    const unsigned short* __restrict__ Qb, const unsigned short* __restrict__ Kb,
    const unsigned short* __restrict__ Vt, const uint32_t* __restrict__ mbits,
    float* __restrict__ attn_out, unsigned short* __restrict__ ctxb)
{
    __shared__ unsigned short panel[16 * 2056];
    __shared__ float sums[4][16];
    __shared__ float obuf[4][32][17];

    const int qt = blockIdx.x & 127;
    const int bh = blockIdx.x >> 7;
    const int b  = bh >> 2;
    const int h  = bh & 3;
    const int Q0 = qt * 16;

    const int tid  = threadIdx.x;
    const int w    = tid >> 6;
    const int lane = tid & 63;
    const int lq   = lane & 15;
    const int g    = lane >> 4;
    const int kvbase = w * 512;

    const unsigned short* Kp = Kb + (size_t)bh * S_ * DK_;
    const unsigned short* Qp = Qb + (size_t)bh * S_ * DK_;
    const unsigned short* Vp = Vt + (size_t)bh * DK_ * S_;

    // Q^T B-fragment: B[dk][q], lane q=lq, dk = g*8..+7
    const short8 qf = *(const short8*)(Qp + (size_t)(Q0 + lq) * DK_ + g * 8);

    const uint32_t* mrow = mbits + ((size_t)b * S_ + Q0 + lq) * 64;

    float sum = 0.f;
    for (int tt = 0; tt < 32; ++tt) {
        const int kv0 = kvbase + tt * 16;
        const short8 kf = *(const short8*)(Kp + (size_t)(kv0 + lq) * DK_ + g * 8);
        f32x4 acc = {0.f, 0.f, 0.f, 0.f};
        acc = __builtin_amdgcn_mfma_f32_16x16x32_bf16(kf, qf, acc, 0, 0, 0);
        // D = S^T tile: col=lq=q, row=g*4+r = kv-in-tile
        const uint32_t mw = mrow[kv0 >> 5] >> ((kv0 & 31) + g * 4);
        float p[4];
        #pragma unroll
        for (int r = 0; r < 4; ++r) {
            const float s = acc[r] * SCALE;
            p[r] = ((mw >> r) & 1u) ? 0.f : __expf(s);
        }
        sum += (p[0] + p[1]) + (p[2] + p[3]);
        uint32_t* dst = (uint32_t*)(panel + lq * 2056 + kv0 + g * 4);
        dst[0] = pack2(p[0], p[1]);
        dst[1] = pack2(p[2], p[3]);
    }
    sum += __shfl_xor(sum, 16);
    sum += __shfl_xor(sum, 32);
    if (lane < 16) sums[w][lane] = sum;
    __syncthreads();

    // (a) normalized attention write, coalesced full rows
    {
        const int q = tid >> 4;
        const int c = tid & 15;
        const float l = sums[0][q] + sums[1][q] + sums[2][q] + sums[3][q];
        const float inv = 1.f / l;
        float* arow = attn_out + ((size_t)bh * S_ + Q0 + q) * S_;
        const unsigned short* prow = panel + q * 2056;
        #pragma unroll 2
        for (int i = 0; i < 16; ++i) {
            const int kv = i * 128 + c * 8;
            const ushort8 p8 = *(const ushort8*)(prow + kv);
            float4 f0, f1;
            f0.x = bf2f(p8[0]) * inv; f0.y = bf2f(p8[1]) * inv;
            f0.z = bf2f(p8[2]) * inv; f0.w = bf2f(p8[3]) * inv;
            f1.x = bf2f(p8[4]) * inv; f1.y = bf2f(p8[5]) * inv;
            f1.z = bf2f(p8[6]) * inv; f1.w = bf2f(p8[7]) * inv;
            *(float4*)(arow + kv)     = f0;
            *(float4*)(arow + kv + 4) = f1;
        }
    }

    // (b) O^T = V^T @ P^T over this wave's kv range
    float invq;
    {
        const float l = sums[0][lq] + sums[1][lq] + sums[2][lq] + sums[3][lq];
        invq = 1.f / l;
    }
    f32x4 od0 = {0.f, 0.f, 0.f, 0.f};
    f32x4 od1 = {0.f, 0.f, 0.f, 0.f};
    for (int ks = 0; ks < 16; ++ks) {
        const int kvb = kvbase + ks * 32;
        const short8 pf = *(const short8*)(panel + lq * 2056 + kvb + g * 8);
        const short8 v0 = *(const short8*)(Vp + (size_t)(lq)      * S_ + kvb + g * 8);
        const short8 v1 = *(const short8*)(Vp + (size_t)(16 + lq) * S_ + kvb + g * 8);
        od0 = __builtin_amdgcn_mfma_f32_16x16x32_bf16(v0, pf, od0, 0, 0, 0);
        od1 = __builtin_amdgcn_mfma_f32_16x16x32_bf16(v1, pf, od1, 0, 0, 0);
    }
    #pragma unroll
    for (int r = 0; r < 4; ++r) {
        obuf[w][g * 4 + r][lq]      = od0[r] * invq;
        obuf[w][16 + g * 4 + r][lq] = od1[r] * invq;
    }
    __syncthreads();

    #pragma unroll
    for (int j = 0; j < 2; ++j) {
        const int idx = tid + j * 256;
        const int d = idx & 31;
        const int q = idx >> 5;
        const float v = obuf[0][d][q] + obuf[1][d][q] + obuf[2][d][q] + obuf[3][d][q];
        ctxb[((size_t)b * S_ + Q0 + q) * D_ + h * DK_ + d] = (unsigned short)bf16b(v);
    }
}

// ---------------------------------------------------------------------------
// Kernel 3: out = LayerNorm(ctxb @ Wfc + resid). MFMA + in-register LN.
// Block = 64 s-rows (4 waves x 16 rows). Grid = B*S/64 = 256.
// ---------------------------------------------------------------------------
__global__ __launch_bounds__(256) void out_kernel(
    const unsigned short* __restrict__ ctxb, const float* __restrict__ resid,
    const unsigned short* __restrict__ Wp, const float* __restrict__ gamma,
    const float* __restrict__ beta, float* __restrict__ out)
{
    const int w    = threadIdx.x >> 6;
    const int lane = threadIdx.x & 63;
    const int lq   = lane & 15;
    const int g    = lane >> 4;
    const size_t row0 = (size_t)blockIdx.x * 64 + w * 16;  // global row b*S+s

    const unsigned short* crow = ctxb + (row0 + lq) * D_;
    short8 afr[4];
    #pragma unroll
    for (int kf = 0; kf < 4; ++kf)
        afr[kf] = *(const short8*)(crow + kf * 32 + g * 8);

    const unsigned short* wp = Wp + 4 * 16384;  // Wfc slot
    float val[8][4];
    #pragma unroll
    for (int nt = 0; nt < 8; ++nt) {
        f32x4 acc = {0.f, 0.f, 0.f, 0.f};
        #pragma unroll
        for (int kf = 0; kf < 4; ++kf) {
            const short8 bfrag = *(const short8*)(wp + ((nt * 4 + kf) * 64 + lane) * 8);
            acc = __builtin_amdgcn_mfma_f32_16x16x32_bf16(afr[kf], bfrag, acc, 0, 0, 0);
        }
        const int n = nt * 16 + lq;
        #pragma unroll
        for (int r = 0; r < 4; ++r)
            val[nt][r] = acc[r] + resid[(row0 + g * 4 + r) * D_ + n];
    }

    float mu[4], rs[4];
    #pragma unroll
    for (int r = 0; r < 4; ++r) {
        float s = 0.f, sq = 0.f;
        #pragma unroll
        for (int nt = 0; nt < 8; ++nt) { s += val[nt][r]; sq += val[nt][r] * val[nt][r]; }
        #pragma unroll
        for (int off = 1; off < 16; off <<= 1) {
            s  += __shfl_xor(s, off);
            sq += __shfl_xor(sq, off);
        }
        const float m = s * (1.f / 128.f);
        mu[r] = m;
        rs[r] = rsqrtf(sq * (1.f / 128.f) - m * m + 1e-5f);
    }

    #pragma unroll
    for (int nt = 0; nt < 8; ++nt) {
        const int n = nt * 16 + lq;
        const float ga = gamma[n], be = beta[n];
        #pragma unroll
        for (int r = 0; r < 4; ++r)
            out[(row0 + g * 4 + r) * D_ + n] = (val[nt][r] - mu[r]) * rs[r] * ga + be;
    }
}

// ---------------------------------------------------------------------------
extern "C" void kernel_launch(void* const* d_in, const int* in_sizes, int n_in,
                              void* d_out, int out_size, void* d_ws, size_t ws_size,
                              hipStream_t stream)
{
    (void)in_sizes; (void)n_in; (void)out_size; (void)ws_size;

    const float* Xq    = (const float*)d_in[0];
    const float* Xk    = (const float*)d_in[1];
    const float* Xv    = (const float*)d_in[2];
    const int*   maski = (const int*)d_in[3];
    const float* Wfc0  = (const float*)d_in[4];
    const float* Wq    = (const float*)d_in[5];
    const float* Wk    = (const float*)d_in[6];
    const float* Wv    = (const float*)d_in[7];
    const float* Wfc   = (const float*)d_in[8];
    const float* gamma = (const float*)d_in[9];
    const float* beta  = (const float*)d_in[10];

    float* out  = (float*)d_out;
    float* attn = out + (size_t)B_ * S_ * D_;

    char* ws = (char*)d_ws;
    float*          resid  = (float*)ws;                          // 8 MB
    unsigned short* ctxb   = (unsigned short*)(ws + (8u  << 20)); // 4 MB
    unsigned short* Qb     = (unsigned short*)(ws + (12u << 20)); // 4 MB
    unsigned short* Kb     = (unsigned short*)(ws + (16u << 20)); // 4 MB
    unsigned short* Vt     = (unsigned short*)(ws + (20u << 20)); // 4 MB
    uint32_t*       mbits  = (uint32_t*)(ws + (24u << 20));       // 4 MB
    unsigned short* Wpack  = (unsigned short*)(ws + (28u << 20)); // 160 KB

    pack_w_kernel<<<dim3(5), dim3(256), 0, stream>>>(Wfc0, Wq, Wk, Wv, Wfc, Wpack);
    pack_mask_kernel<<<dim3(2048), dim3(256), 0, stream>>>(
        maski, (unsigned long long*)mbits);
    proj_kernel<<<dim3(B_ * (S_ / 16)), dim3(256), 0, stream>>>(
        Xq, Xk, Xv, Wpack, resid, Qb, Kb, Vt);
    attn_kernel<<<dim3(B_ * H_ * (S_ / 16)), dim3(256), 0, stream>>>(
        Qb, Kb, Vt, mbits, attn, ctxb);
    out_kernel<<<dim3(B_ * S_ / 64), dim3(256), 0, stream>>>(
        ctxb, resid, Wpack, gamma, beta, out);
}